// Round 1
// baseline (242.342 us; speedup 1.0000x reference)
//
#include <hip/hip_runtime.h>

// Problem constants
#define BB 8
#define CC 64
#define OO 64
#define HH 128
#define WW 128
#define HWSZ (HH * WW)      // 16384
#define KK 9                // 3x3 taps
#define II (KK * CC)        // 576

__device__ __forceinline__ int iclamp(int v, int lo, int hi) {
    return v < lo ? lo : (v > hi ? hi : v);
}

// Transpose weight [O][C*K] (flat, o-major) -> wt[i][o] (i-major) so the
// main kernel reads weight rows with wave-uniform contiguous addresses
// (compiler scalarizes to s_load_dwordx16).
__global__ void transpose_w_kernel(const float* __restrict__ w, float* __restrict__ wt) {
    int idx = blockIdx.x * 256 + threadIdx.x;
    if (idx < OO * II) {
        int o = idx / II;
        int i = idx % II;
        wt[i * OO + o] = w[idx];
    }
}

// TRANSPOSED=1: wmat is wt[i][o] (stride 1 over o)
// TRANSPOSED=0: wmat is original w[o][i] (stride II over o) — fallback
template <int TRANSPOSED>
__global__ __launch_bounds__(256) void deform_conv_kernel(
        const float* __restrict__ x,      // [B][C][H][W]
        const float* __restrict__ off,    // [B][2K][H][W], ch = k*2 + {0:gx,1:gy}
        const float* __restrict__ wmat,
        const float* __restrict__ bias,   // [O]
        float* __restrict__ out) {        // [B][O][H][W]
    const int b = blockIdx.y;
    const int p = blockIdx.x * 256 + threadIdx.x;   // pixel index in [0, HWSZ)
    const int wo = p & (WW - 1);
    const int ho = p >> 7;

    const float* xb   = x   + (size_t)b * CC * HWSZ;
    const float* offb = off + (size_t)b * 2 * KK * HWSZ + p;

    float acc[OO];
#pragma unroll
    for (int o = 0; o < OO; ++o) acc[o] = 0.0f;

#pragma unroll 1
    for (int k = 0; k < KK; ++k) {
        // grid position in PADDED coords (pad=1). Base grid is the top-left
        // tap only (reference adds no per-tap kh/kw).
        const float gx = offb[(size_t)(2 * k + 0) * HWSZ] + (float)wo;
        const float gy = offb[(size_t)(2 * k + 1) * HWSZ] + (float)ho;

        const float fxf = floorf(gx);
        const float fyf = floorf(gy);
        const float fx = gx - fxf;          // in [0,1)
        const float fy = gy - fyf;
        const int xi = (int)fxf;            // padded coord of left column
        const int yi = (int)fyf;            // padded coord of top row

        // Four corners in UNPADDED coords (padded - 1)
        const int ux0 = xi - 1, ux1 = xi;
        const int uy0 = yi - 1, uy1 = yi;

        const float vx0 = ((unsigned)ux0 < (unsigned)WW) ? 1.0f : 0.0f;
        const float vx1 = ((unsigned)ux1 < (unsigned)WW) ? 1.0f : 0.0f;
        const float vy0 = ((unsigned)uy0 < (unsigned)HH) ? 1.0f : 0.0f;
        const float vy1 = ((unsigned)uy1 < (unsigned)HH) ? 1.0f : 0.0f;

        // Bilinear weights with validity folded in (channel-independent)
        const float w00 = (1.0f - fy) * (1.0f - fx) * vy0 * vx0;
        const float w01 = (1.0f - fy) * fx          * vy0 * vx1;
        const float w10 = fy          * (1.0f - fx) * vy1 * vx0;
        const float w11 = fy          * fx          * vy1 * vx1;

        const int cx0 = iclamp(ux0, 0, WW - 1), cx1 = iclamp(ux1, 0, WW - 1);
        const int cy0 = iclamp(uy0, 0, HH - 1), cy1 = iclamp(uy1, 0, HH - 1);
        const int i00 = cy0 * WW + cx0;
        const int i01 = cy0 * WW + cx1;
        const int i10 = cy1 * WW + cx0;
        const int i11 = cy1 * WW + cx1;

#pragma unroll 4
        for (int c = 0; c < CC; ++c) {
            const float* xc = xb + (size_t)c * HWSZ;
            const float v = w00 * xc[i00] + w01 * xc[i01]
                          + w10 * xc[i10] + w11 * xc[i11];
            if (TRANSPOSED) {
                const float* wrow = wmat + (size_t)(k * CC + c) * OO;  // uniform addr
#pragma unroll
                for (int o = 0; o < OO; ++o) acc[o] = fmaf(wrow[o], v, acc[o]);
            } else {
                const float* wrow = wmat + (size_t)(k * CC + c);       // uniform addr
#pragma unroll
                for (int o = 0; o < OO; ++o) acc[o] = fmaf(wrow[(size_t)o * II], v, acc[o]);
            }
        }
    }

    float* outb = out + (size_t)b * OO * HWSZ + p;
#pragma unroll
    for (int o = 0; o < OO; ++o) outb[(size_t)o * HWSZ] = acc[o] + bias[o];
}

extern "C" void kernel_launch(void* const* d_in, const int* in_sizes, int n_in,
                              void* d_out, int out_size, void* d_ws, size_t ws_size,
                              hipStream_t stream) {
    const float* x    = (const float*)d_in[0];
    const float* off  = (const float*)d_in[1];
    const float* w    = (const float*)d_in[2];
    const float* bias = (const float*)d_in[3];
    float* out = (float*)d_out;

    const dim3 grid(HWSZ / 256, BB);
    const dim3 block(256);

    const size_t wt_bytes = (size_t)II * OO * sizeof(float);
    if (ws_size >= wt_bytes) {
        float* wt = (float*)d_ws;
        transpose_w_kernel<<<(OO * II + 255) / 256, 256, 0, stream>>>(w, wt);
        deform_conv_kernel<1><<<grid, block, 0, stream>>>(x, off, wt, bias, out);
    } else {
        deform_conv_kernel<0><<<grid, block, 0, stream>>>(x, off, w, bias, out);
    }
}

// Round 2
// 95.497 us; speedup vs baseline: 2.5377x; 2.5377x over previous
//
#include <hip/hip_runtime.h>

// Problem constants
#define BB 8
#define CC 64
#define OO 64
#define HH 128
#define WWI 128
#define HWSZ (HH * WWI)     // 16384
#define KK 9                // 3x3 taps
#define II (KK * CC)        // 576

typedef __attribute__((ext_vector_type(8))) short bf16x8;
typedef __attribute__((ext_vector_type(8))) unsigned short ushort8;
typedef __attribute__((ext_vector_type(4))) float f32x4;

__device__ __forceinline__ int iclamp(int v, int lo, int hi) {
    return v < lo ? lo : (v > hi ? hi : v);
}
__device__ __forceinline__ unsigned short f2bf(float f) {  // RNE
    unsigned u = __float_as_uint(f);
    return (unsigned short)((u + 0x7fffu + ((u >> 16) & 1u)) >> 16);
}
__device__ __forceinline__ float bf2f(unsigned short s) {
    return __uint_as_float(((unsigned)s) << 16);
}

// ---------- prep 1: x [B][C][H][W] f32 -> xt [B][H][W][C] bf16 (LDS transpose)
__global__ __launch_bounds__(256) void prep_xt(const float* __restrict__ x,
                                               unsigned short* __restrict__ xt) {
    __shared__ float tile[64][65];
    const int b = blockIdx.y;
    const int p0 = blockIdx.x * 64;
    const int t = threadIdx.x;
    const int a = t >> 6;   // 0..3
    const int q = t & 63;   // 0..63
    const float* xb = x + (size_t)b * CC * HWSZ + p0;
#pragma unroll
    for (int r = 0; r < 16; ++r) {
        int c = r * 4 + a;
        tile[c][q] = xb[(size_t)c * HWSZ + q];   // coalesced read
    }
    __syncthreads();
    unsigned short* xo = xt + ((size_t)b * HWSZ + p0) * CC;
#pragma unroll
    for (int r = 0; r < 16; ++r) {
        int pl = r * 4 + a;
        xo[(size_t)pl * CC + q] = f2bf(tile[q][pl]);  // coalesced 2B x 64 write
    }
}

// ---------- prep 2: w f32 -> bf16 (same flat [O][II] layout)
__global__ void prep_wb(const float* __restrict__ w, unsigned short* __restrict__ wb) {
    int i = blockIdx.x * 256 + threadIdx.x;
    if (i < OO * II) wb[i] = f2bf(w[i]);
}

// ---------- main: per block 64 pixels x 64 outputs, K=576 tap-by-tap via MFMA
__global__ __launch_bounds__(256) void deform_mfma(
        const unsigned short* __restrict__ xt,   // [B][H][W][C] bf16
        const float* __restrict__ off,           // [B][2K][H][W]
        const unsigned short* __restrict__ wb,   // [O][II] bf16
        const float* __restrict__ bias,          // [O]
        float* __restrict__ out) {               // [B][O][H][W]
    constexpr int PPB = 64;            // pixels per block
    constexpr int LROW = 72;           // 64 data + 8 pad (shorts) -> 144 B rows
    __shared__ unsigned short Sb[2][PPB][LROW];  // sampled tap slab
    __shared__ unsigned short Wb[2][OO][LROW];   // weight tap slab

    const int b = blockIdx.y;
    const int p0 = blockIdx.x * PPB;
    const int t = threadIdx.x;
    const int wave = t >> 6;
    const int lane = t & 63;

    // sampling role: thread -> (pixel, channel-quarter)
    const int spx = t & 63;
    const int scq = t >> 6;            // 16 channels each
    const int p = p0 + spx;
    const int wo = p & (WWI - 1);
    const int ho = p >> 7;
    const float* offp = off + (size_t)b * 2 * KK * HWSZ + p;
    const unsigned short* xtb = xt + (size_t)b * HWSZ * CC;

    // W staging role: thread -> (o row, 16-channel chunk)
    const int so = t >> 2;
    const int swc = (t & 3) * 16;

    // MFMA role
    const int fm = lane & 15;          // m (A row) / n (B col) within tile
    const int fk = (lane >> 4) * 8;    // k base within 32-chunk
    f32x4 acc[4];
#pragma unroll
    for (int m = 0; m < 4; ++m) acc[m] = (f32x4)(0.0f);

    auto stage = [&](int k, int buf) {
        // ---- sample 16 channels of tap k for pixel spx ----
        const float gx = offp[(size_t)(2 * k + 0) * HWSZ] + (float)wo;  // padded coords
        const float gy = offp[(size_t)(2 * k + 1) * HWSZ] + (float)ho;
        const float fxf = floorf(gx), fyf = floorf(gy);
        const float fx = gx - fxf, fy = gy - fyf;
        const int ux0 = (int)fxf - 1, ux1 = (int)fxf;      // unpadded
        const int uy0 = (int)fyf - 1, uy1 = (int)fyf;
        const float vx0 = ((unsigned)ux0 < (unsigned)WWI) ? 1.0f : 0.0f;
        const float vx1 = ((unsigned)ux1 < (unsigned)WWI) ? 1.0f : 0.0f;
        const float vy0 = ((unsigned)uy0 < (unsigned)HH) ? 1.0f : 0.0f;
        const float vy1 = ((unsigned)uy1 < (unsigned)HH) ? 1.0f : 0.0f;
        const float w00 = (1.0f - fy) * (1.0f - fx) * vy0 * vx0;
        const float w01 = (1.0f - fy) * fx          * vy0 * vx1;
        const float w10 = fy          * (1.0f - fx) * vy1 * vx0;
        const float w11 = fy          * fx          * vy1 * vx1;
        const int cx0 = iclamp(ux0, 0, WWI - 1), cx1 = iclamp(ux1, 0, WWI - 1);
        const int cy0 = iclamp(uy0, 0, HH - 1),  cy1 = iclamp(uy1, 0, HH - 1);
        const unsigned short* r00 = xtb + ((size_t)(cy0 * WWI + cx0) * CC + scq * 16);
        const unsigned short* r01 = xtb + ((size_t)(cy0 * WWI + cx1) * CC + scq * 16);
        const unsigned short* r10 = xtb + ((size_t)(cy1 * WWI + cx0) * CC + scq * 16);
        const unsigned short* r11 = xtb + ((size_t)(cy1 * WWI + cx1) * CC + scq * 16);
        const ushort8 a0 = ((const ushort8*)r00)[0], a1 = ((const ushort8*)r00)[1];
        const ushort8 b0 = ((const ushort8*)r01)[0], b1 = ((const ushort8*)r01)[1];
        const ushort8 c0 = ((const ushort8*)r10)[0], c1 = ((const ushort8*)r10)[1];
        const ushort8 d0 = ((const ushort8*)r11)[0], d1 = ((const ushort8*)r11)[1];
        ushort8 o0, o1;
#pragma unroll
        for (int j = 0; j < 8; ++j) {
            float v = w00 * bf2f(a0[j]) + w01 * bf2f(b0[j])
                    + w10 * bf2f(c0[j]) + w11 * bf2f(d0[j]);
            o0[j] = f2bf(v);
            float v2 = w00 * bf2f(a1[j]) + w01 * bf2f(b1[j])
                     + w10 * bf2f(c1[j]) + w11 * bf2f(d1[j]);
            o1[j] = f2bf(v2);
        }
        *(ushort8*)&Sb[buf][spx][scq * 16]     = o0;
        *(ushort8*)&Sb[buf][spx][scq * 16 + 8] = o1;
        // ---- stage W slab for tap k: wb[o][k*64 .. k*64+64) ----
        const unsigned short* wp = wb + (size_t)so * II + k * 64 + swc;
        *(ushort8*)&Wb[buf][so][swc]     = ((const ushort8*)wp)[0];
        *(ushort8*)&Wb[buf][so][swc + 8] = ((const ushort8*)wp)[1];
    };

    stage(0, 0);
    __syncthreads();

#pragma unroll 1
    for (int k = 0; k < KK; ++k) {
        const int cur = k & 1;
        if (k + 1 < KK) stage(k + 1, cur ^ 1);   // prefetch next tap (other buffer)
        const int nrow = wave * 16 + fm;
#pragma unroll
        for (int kc = 0; kc < 2; ++kc) {
            const bf16x8 bfrag = *(const bf16x8*)&Sb[cur][nrow][kc * 32 + fk];
#pragma unroll
            for (int m = 0; m < 4; ++m) {
                const bf16x8 afrag = *(const bf16x8*)&Wb[cur][m * 16 + fm][kc * 32 + fk];
                acc[m] = __builtin_amdgcn_mfma_f32_16x16x32_bf16(afrag, bfrag, acc[m], 0, 0, 0);
            }
        }
        __syncthreads();
    }

    // epilogue: D layout col = lane&15, row = (lane>>4)*4 + j
    float* outb = out + (size_t)b * OO * HWSZ + p0 + wave * 16 + (lane & 15);
#pragma unroll
    for (int m = 0; m < 4; ++m) {
        const int ob = m * 16 + (lane >> 4) * 4;
        const float4 bs = *(const float4*)(bias + ob);
#pragma unroll
        for (int j = 0; j < 4; ++j) {
            outb[(size_t)(ob + j) * HWSZ] = acc[m][j] + ((const float*)&bs)[j];
        }
    }
}

// ---------- fallback (round-1 fp32 path, used only if ws too small) ----------
__global__ __launch_bounds__(256) void deform_conv_fallback(
        const float* __restrict__ x, const float* __restrict__ off,
        const float* __restrict__ wmat, const float* __restrict__ bias,
        float* __restrict__ out) {
    const int b = blockIdx.y;
    const int p = blockIdx.x * 256 + threadIdx.x;
    const int wo = p & (WWI - 1);
    const int ho = p >> 7;
    const float* xb = x + (size_t)b * CC * HWSZ;
    const float* offb = off + (size_t)b * 2 * KK * HWSZ + p;
    float acc[OO];
#pragma unroll
    for (int o = 0; o < OO; ++o) acc[o] = 0.0f;
#pragma unroll 1
    for (int k = 0; k < KK; ++k) {
        const float gx = offb[(size_t)(2 * k + 0) * HWSZ] + (float)wo;
        const float gy = offb[(size_t)(2 * k + 1) * HWSZ] + (float)ho;
        const float fxf = floorf(gx), fyf = floorf(gy);
        const float fx = gx - fxf, fy = gy - fyf;
        const int ux0 = (int)fxf - 1, ux1 = (int)fxf;
        const int uy0 = (int)fyf - 1, uy1 = (int)fyf;
        const float vx0 = ((unsigned)ux0 < (unsigned)WWI) ? 1.0f : 0.0f;
        const float vx1 = ((unsigned)ux1 < (unsigned)WWI) ? 1.0f : 0.0f;
        const float vy0 = ((unsigned)uy0 < (unsigned)HH) ? 1.0f : 0.0f;
        const float vy1 = ((unsigned)uy1 < (unsigned)HH) ? 1.0f : 0.0f;
        const float w00 = (1.0f - fy) * (1.0f - fx) * vy0 * vx0;
        const float w01 = (1.0f - fy) * fx * vy0 * vx1;
        const float w10 = fy * (1.0f - fx) * vy1 * vx0;
        const float w11 = fy * fx * vy1 * vx1;
        const int cx0 = iclamp(ux0, 0, WWI - 1), cx1 = iclamp(ux1, 0, WWI - 1);
        const int cy0 = iclamp(uy0, 0, HH - 1), cy1 = iclamp(uy1, 0, HH - 1);
        const int i00 = cy0 * WWI + cx0, i01 = cy0 * WWI + cx1;
        const int i10 = cy1 * WWI + cx0, i11 = cy1 * WWI + cx1;
#pragma unroll 4
        for (int c = 0; c < CC; ++c) {
            const float* xc = xb + (size_t)c * HWSZ;
            const float v = w00 * xc[i00] + w01 * xc[i01] + w10 * xc[i10] + w11 * xc[i11];
            const float* wrow = wmat + (size_t)(k * CC + c);
#pragma unroll
            for (int o = 0; o < OO; ++o) acc[o] = fmaf(wrow[(size_t)o * II], v, acc[o]);
        }
    }
    float* outb = out + (size_t)b * OO * HWSZ + p;
#pragma unroll
    for (int o = 0; o < OO; ++o) outb[(size_t)o * HWSZ] = acc[o] + bias[o];
}

extern "C" void kernel_launch(void* const* d_in, const int* in_sizes, int n_in,
                              void* d_out, int out_size, void* d_ws, size_t ws_size,
                              hipStream_t stream) {
    const float* x    = (const float*)d_in[0];
    const float* off  = (const float*)d_in[1];
    const float* w    = (const float*)d_in[2];
    const float* bias = (const float*)d_in[3];
    float* out = (float*)d_out;

    const size_t xt_bytes = (size_t)BB * HWSZ * CC * sizeof(unsigned short); // 16.78 MB
    const size_t wb_bytes = (size_t)OO * II * sizeof(unsigned short);        // 72 KB

    if (ws_size >= xt_bytes + wb_bytes) {
        unsigned short* xt = (unsigned short*)d_ws;
        unsigned short* wbp = (unsigned short*)((char*)d_ws + xt_bytes);
        prep_xt<<<dim3(HWSZ / 64, BB), 256, 0, stream>>>(x, xt);
        prep_wb<<<(OO * II + 255) / 256, 256, 0, stream>>>(w, wbp);
        deform_mfma<<<dim3(HWSZ / 64, BB), 256, 0, stream>>>(xt, off, wbp, bias, out);
    } else {
        deform_conv_fallback<<<dim3(HWSZ / 256, BB), 256, 0, stream>>>(x, off, w, bias, out);
    }
}